// Round 13
// baseline (322.991 us; speedup 1.0000x reference)
//
#include <hip/hip_runtime.h>

typedef __attribute__((ext_vector_type(8))) __bf16 bf16x8;
typedef __attribute__((ext_vector_type(4))) float f32x4;
typedef __attribute__((ext_vector_type(8))) unsigned short ushortx8;

#define MC 384   // max messages staged in LDS per block
#define MCP 448  // MC + 64 overrun pad

__device__ inline unsigned short f2bf(float f) {
  unsigned int u = __float_as_uint(f);
  unsigned int r = (u + 0x7FFFu + ((u >> 16) & 1u)) >> 16;  // RNE
  return (unsigned short)r;
}
__device__ inline float bflo(unsigned u) { return __uint_as_float(u << 16); }
__device__ inline float bfhi(unsigned u) { return __uint_as_float(u & 0xFFFF0000u); }

// ---------------- prep: fused conv | tconv(LDS transpose) | hist | detect ----------------
__global__ __launch_bounds__(256) void prep_kernel(const float* __restrict__ x,
                                                   unsigned short* __restrict__ xb, int total8,
                                                   const float* __restrict__ bases,
                                                   unsigned short* __restrict__ bmt,
                                                   const int* __restrict__ src,
                                                   const int* __restrict__ tgt, int E,
                                                   int* __restrict__ cnt,
                                                   const unsigned char* __restrict__ mask,
                                                   int mbytes, int* __restrict__ flag_out,
                                                   int CB, int TB, int HB) {
  __shared__ float tile_s[32][33];
  __shared__ int nz_off, big;
  int bid = blockIdx.x;
  if (bid < CB) {
    int id = bid * 256 + threadIdx.x;
    if (id >= total8) return;
    f32x4 f0 = ((const f32x4*)x)[2 * id];
    f32x4 f1 = ((const f32x4*)x)[2 * id + 1];
    ushortx8 r;
    r[0] = f2bf(f0[0]); r[1] = f2bf(f0[1]); r[2] = f2bf(f0[2]); r[3] = f2bf(f0[3]);
    r[4] = f2bf(f1[0]); r[5] = f2bf(f1[1]); r[6] = f2bf(f1[2]); r[7] = f2bf(f1[3]);
    ((ushortx8*)xb)[id] = r;
  } else if (bid < CB + TB) {
    // bmt[o][k]=bases[b][d][o], k=b*128+d — 32x32 LDS tile transpose, coalesced both sides
    int bid2 = bid - CB;                 // 0..127
    int b = bid2 >> 4, tile = bid2 & 15;
    int o0 = (tile >> 2) * 32, d0 = (tile & 3) * 32;
    int tx = threadIdx.x & 31, ty = threadIdx.x >> 5;
#pragma unroll
    for (int i = 0; i < 4; ++i) {
      int dl = ty + i * 8;
      tile_s[dl][tx] = bases[b * 16384 + (d0 + dl) * 128 + (o0 + tx)];
    }
    __syncthreads();
#pragma unroll
    for (int i = 0; i < 4; ++i) {
      int ol = ty + i * 8;
      bmt[(size_t)(o0 + ol) * 1024 + b * 128 + d0 + tx] = f2bf(tile_s[tx][ol]);
    }
  } else if (bid < CB + TB + HB) {
    int i = (bid - CB - TB) * 256 + threadIdx.x;
    if (i >= E) return;
    atomicAdd(&cnt[tgt[i]], 1);
    atomicAdd(&cnt[src[i]], 1);
  } else {
    if (threadIdx.x == 0) { nz_off = 0; big = 0; }
    __syncthreads();
    int lnz = 0, lbig = 0;
    for (int i = threadIdx.x; i < mbytes; i += 256) {
      unsigned char v = mask[i];
      if ((i & 3) && v) lnz++;
      if (v > 1) lbig++;
    }
    if (lnz) atomicAdd(&nz_off, lnz);
    if (lbig) atomicAdd(&big, lbig);
    __syncthreads();
    if (threadIdx.x == 0) *flag_out = (nz_off == 0) ? 0 : ((big == 0) ? 1 : 2);
  }
}

// ---------------- scanA: per-block sums ----------------
__global__ __launch_bounds__(256) void scanA_kernel(const int* __restrict__ cnt, int N,
                                                    int* __restrict__ bsum) {
  __shared__ int s[256];
  int t = threadIdx.x, i = blockIdx.x * 256 + t;
  s[t] = (i < N) ? cnt[i] : 0;
  __syncthreads();
#pragma unroll
  for (int off = 128; off > 0; off >>= 1) {
    if (t < off) s[t] += s[t + off];
    __syncthreads();
  }
  if (t == 0) bsum[blockIdx.x] = s[0];
}

// ---------------- scanB: fused block-prefix + per-element exclusive scan + cursor ----------------
__global__ __launch_bounds__(256) void scanB_kernel(const int* __restrict__ cnt, int N,
                                                    const int* __restrict__ bsum, int NB,
                                                    int* __restrict__ base,
                                                    int* __restrict__ cursor) {
  __shared__ int s[256];
  __shared__ int spref;
  int t = threadIdx.x, bid = blockIdx.x;
  int acc = 0;
  for (int i = t; i < bid; i += 256) acc += bsum[i];
  s[t] = acc;
  __syncthreads();
#pragma unroll
  for (int off = 128; off > 0; off >>= 1) {
    if (t < off) s[t] += s[t + off];
    __syncthreads();
  }
  if (t == 0) spref = s[0];
  __syncthreads();
  int pref = spref;
  __syncthreads();
  int i = bid * 256 + t;
  int c = (i < N) ? cnt[i] : 0;
  s[t] = c;
  __syncthreads();
  for (int off = 1; off < 256; off <<= 1) {
    int x = (t >= off) ? s[t - off] : 0;
    __syncthreads();
    s[t] += x;
    __syncthreads();
  }
  if (i < N) {
    int v = pref + s[t] - c;
    base[i] = v;
    cursor[i] = v;
  }
  if (bid == NB - 1 && t == 255) base[N] = pref + s[255];
}

// ---------------- scatter: messages (src) + premultiplied bf16 coeffs; pad folded in ----------------
__global__ __launch_bounds__(256) void scatter_kernel(const int* __restrict__ src,
                                                      const int* __restrict__ tgt,
                                                      const int* __restrict__ et,
                                                      const float* __restrict__ ew, int E,
                                                      const float* __restrict__ rbw,
                                                      int* __restrict__ cursor,
                                                      unsigned* __restrict__ msrc,
                                                      uint4* __restrict__ mcoef) {
  __shared__ float ctab[264];
  for (int i = threadIdx.x; i < 264; i += 256) ctab[i] = rbw[i];
  __syncthreads();
  if (blockIdx.x == 0 && threadIdx.x < 80) {  // zero pad tail (overrun region)
    msrc[2 * E + threadIdx.x] = 0u;
    mcoef[2 * E + threadIdx.x] = make_uint4(0u, 0u, 0u, 0u);
  }
  int i = blockIdx.x * 256 + threadIdx.x;
  if (i >= E) return;
  int s = src[i], g = tgt[i], r = et[i];
  float w = ew[i];
  uint4 cv;
  {
    const float* c = &ctab[r * 8];
    cv.x = (unsigned)f2bf(w * c[0]) | ((unsigned)f2bf(w * c[1]) << 16);
    cv.y = (unsigned)f2bf(w * c[2]) | ((unsigned)f2bf(w * c[3]) << 16);
    cv.z = (unsigned)f2bf(w * c[4]) | ((unsigned)f2bf(w * c[5]) << 16);
    cv.w = (unsigned)f2bf(w * c[6]) | ((unsigned)f2bf(w * c[7]) << 16);
  }
  int s1 = atomicAdd(&cursor[g], 1);
  msrc[s1] = (unsigned)s;
  mcoef[s1] = cv;
  int s2 = atomicAdd(&cursor[s], 1);
  msrc[s2] = (unsigned)g;
  mcoef[s2] = cv;
}

// ---------------- pipelined gather helpers ----------------
template <bool LDSM>
__device__ __forceinline__ void pf_round(const uint2* __restrict__ xb64,
                                         const unsigned* lms, const unsigned* __restrict__ gms,
                                         int B0, int gcap, int R0,
                                         int loc0, int loc1, int q, int ll, unsigned Nm1,
                                         uint2 (&xq)[4]) {
  // caller guarantees q < RT
  int loc = (q < R0) ? loc0 : loc1;
  int m = ((q < R0) ? q : q - R0) * 4;
#pragma unroll
  for (int s = 0; s < 4; ++s) {
    int idx = loc + m + s;
    unsigned row;
    if (LDSM) row = lms[min(idx, MCP - 1)];
    else      row = gms[min(B0 + idx, gcap)];
    row = min(row & 0xFFFFFu, Nm1);
    xq[s] = xb64[(size_t)row * 32 + ll];
  }
}

template <bool LDSM>
__device__ __forceinline__ void fma_round(const uint4* lmc, const uint4* __restrict__ gmc,
                                          int B0, int gcap, int R0,
                                          int loc0, int cnt0, int loc1, int cnt1,
                                          int r, const uint2 (&xq)[4], f32x4 (&z)[8]) {
  int loc = (r < R0) ? loc0 : loc1;
  int cnt = (r < R0) ? cnt0 : cnt1;
  int mb = ((r < R0) ? r : r - R0) * 4;
#pragma unroll
  for (int s = 0; s < 4; ++s) {
    int idx = loc + mb + s;
    uint4 cf;
    if (LDSM) cf = lmc[min(idx, MCP - 1)];
    else      cf = gmc[min(B0 + idx, gcap)];
    unsigned vm = ((mb + s) < cnt) ? 0xFFFFFFFFu : 0u;
    unsigned c0 = cf.x & vm, c1 = cf.y & vm, c2 = cf.z & vm, c3 = cf.w & vm;
    f32x4 xv = {bflo(xq[s].x), bfhi(xq[s].x), bflo(xq[s].y), bfhi(xq[s].y)};
    float a;
    a = bflo(c0); z[0] = __builtin_elementwise_fma((f32x4){a, a, a, a}, xv, z[0]);
    a = bfhi(c0); z[1] = __builtin_elementwise_fma((f32x4){a, a, a, a}, xv, z[1]);
    a = bflo(c1); z[2] = __builtin_elementwise_fma((f32x4){a, a, a, a}, xv, z[2]);
    a = bfhi(c1); z[3] = __builtin_elementwise_fma((f32x4){a, a, a, a}, xv, z[3]);
    a = bflo(c2); z[4] = __builtin_elementwise_fma((f32x4){a, a, a, a}, xv, z[4]);
    a = bfhi(c2); z[5] = __builtin_elementwise_fma((f32x4){a, a, a, a}, xv, z[5]);
    a = bflo(c3); z[6] = __builtin_elementwise_fma((f32x4){a, a, a, a}, xv, z[6]);
    a = bfhi(c3); z[7] = __builtin_elementwise_fma((f32x4){a, a, a, a}, xv, z[7]);
  }
}

__device__ __forceinline__ void seed_z(const float* __restrict__ rbw, float ms, uint2 xs,
                                       f32x4 (&z)[8]) {
  f32x4 xv0 = {bflo(xs.x), bfhi(xs.x), bflo(xs.y), bfhi(xs.y)};
#pragma unroll
  for (int b = 0; b < 8; ++b) {
    float a = ms * rbw[256 + b];
    z[b] = (f32x4){a, a, a, a} * xv0;
  }
}

__device__ __forceinline__ void flush_z(char* smem, int rowS, int ll, const f32x4 (&z)[8]) {
#pragma unroll
  for (int b = 0; b < 8; ++b) {
    unsigned d0 = (unsigned)f2bf(z[b][0]) | ((unsigned)f2bf(z[b][1]) << 16);
    unsigned d1 = (unsigned)f2bf(z[b][2]) | ((unsigned)f2bf(z[b][3]) << 16);
    int byte = rowS * 2048 + ((b * 256 + ll * 8) ^ ((rowS & 7) << 4));
    *(uint2*)(smem + byte) = make_uint2(d0, d1);
  }
}

// ---------------- K: flat cross-pair distance-2 pipelined gather + block MFMA ----------------
// block = 512 thr (8 waves), owns 32 targets; wave owns 4 targets (2 per half-wave stream).
template <bool LDSM>
__device__ __forceinline__ void wave_gather(const uint2* __restrict__ xb64,
                                            const unsigned* lms, const uint4* lmc,
                                            const unsigned* __restrict__ gms,
                                            const uint4* __restrict__ gmc,
                                            char* smem, const float* __restrict__ rbw,
                                            int B0, int gcap, int R0, int RT,
                                            int loc0, int cnt0, int loc1, int cnt1,
                                            int row0, int row1, float ms0, float ms1,
                                            uint2 xs0, uint2 xs1, int ll, unsigned Nm1) {
  f32x4 z[8];
  uint2 q0[4], q1[4], q2[4];
#define PF(q_, buf_) if ((q_) < RT) pf_round<LDSM>(xb64, lms, gms, B0, gcap, R0, loc0, loc1, (q_), ll, Nm1, buf_)
#define FMAR(r_, buf_) fma_round<LDSM>(lmc, gmc, B0, gcap, R0, loc0, cnt0, loc1, cnt1, (r_), buf_, z)
#define BNDRY(r_) if ((r_) == R0) { flush_z(smem, row0, ll, z); seed_z(rbw, ms1, xs1, z); }
  PF(0, q0);
  PF(1, q1);
  seed_z(rbw, ms0, xs0, z);
  int r = 0;
  while (r + 3 <= RT) {
    PF(r + 2, q2); BNDRY(r); FMAR(r, q0);
    PF(r + 3, q0); BNDRY(r + 1); FMAR(r + 1, q1);
    PF(r + 4, q1); BNDRY(r + 2); FMAR(r + 2, q2);
    r += 3;
  }
  if (r < RT) {
    BNDRY(r); FMAR(r, q0); ++r;
    if (r < RT) { BNDRY(r); FMAR(r, q1); ++r; }
  }
  if (R0 == RT) { flush_z(smem, row0, ll, z); seed_z(rbw, ms1, xs1, z); }
  flush_z(smem, row1, ll, z);
#undef PF
#undef FMAR
#undef BNDRY
}

__global__ __launch_bounds__(512, 4) void gather_kernel(
    const uint2* __restrict__ xb64, const unsigned short* __restrict__ bmt,
    const int* __restrict__ base, const unsigned* __restrict__ msrc,
    const uint4* __restrict__ mcoef, const float* __restrict__ rbw,
    const void* __restrict__ maskp, const int* __restrict__ flag_p,
    float* __restrict__ out, int N, int gcap) {
  extern __shared__ char smem[];
  unsigned* lms = (unsigned*)(smem + 65536);
  uint4* lmc = (uint4*)(smem + 65536 + MCP * 4);
  int* lbase = (int*)(smem + 65536 + MCP * 4 + MCP * 16);
  int t = threadIdx.x;
  int wid = t >> 6, l = t & 63;
  int hw = l >> 5, ll = l & 31;
  int t0 = blockIdx.x * 32;
  int flag = *flag_p;  // uniform
  unsigned Nm1 = (unsigned)(N - 1);

  if (t < 33) lbase[t] = base[min(t0 + t, N)];
  int B0 = __builtin_amdgcn_readfirstlane(base[min(t0, N)]);
  int B1 = __builtin_amdgcn_readfirstlane(base[min(t0 + 32, N)]);
  int nm = B1 - B0;
  bool use_lds = (nm <= MC);
  if (use_lds) {
    for (int i = t; i < nm; i += 512) {
      lms[i] = msrc[B0 + i];
      lmc[i] = mcoef[B0 + i];
    }
    int pz = nm + t;
    if (t < 64 && pz < MCP) {
      lms[pz] = 0u;
      lmc[pz] = make_uint4(0u, 0u, 0u, 0u);
    }
  }
  __syncthreads();

  {
    int jA0 = wid * 4;
    int g0 = __builtin_amdgcn_readfirstlane(lbase[jA0]);
    int g1 = __builtin_amdgcn_readfirstlane(lbase[jA0 + 1]);
    int g2 = __builtin_amdgcn_readfirstlane(lbase[jA0 + 2]);
    int g3 = __builtin_amdgcn_readfirstlane(lbase[jA0 + 3]);
    int g4 = __builtin_amdgcn_readfirstlane(lbase[jA0 + 4]);
    int tgb = t0 + jA0;
    int cA0 = (tgb < N) ? (g1 - g0) : 0;
    int cB0 = (tgb + 1 < N) ? (g2 - g1) : 0;
    int cA1 = (tgb + 2 < N) ? (g3 - g2) : 0;
    int cB1 = (tgb + 3 < N) ? (g4 - g3) : 0;
    int lA0 = g0 - B0, lB0 = g1 - B0, lA1 = g2 - B0, lB1 = g3 - B0;
    int loc0 = hw ? lB0 : lA0, cnt0 = hw ? cB0 : cA0;
    int loc1 = hw ? lB1 : lA1, cnt1 = hw ? cB1 : cA1;
    int row0 = jA0 + hw, row1 = jA0 + 2 + hw;
    int tgS0 = t0 + row0, tgS1 = t0 + row1;
    int tc0 = min(tgS0, N - 1), tc1 = min(tgS1, N - 1);
    int R0 = (max(cA0, cB0) + 3) >> 2;
    int R1 = (max(cA1, cB1) + 3) >> 2;
    int RT = R0 + R1;
    // early self-row loads + mask
    uint2 xs0 = xb64[(size_t)tc0 * 32 + ll];
    uint2 xs1 = xb64[(size_t)tc1 * 32 + ll];
    int k0, k1;
    if (flag == 0) {
      k0 = ((const int*)maskp)[tc0] != 0; k1 = ((const int*)maskp)[tc1] != 0;
    } else if (flag == 1) {
      k0 = ((const unsigned char*)maskp)[tc0] != 0; k1 = ((const unsigned char*)maskp)[tc1] != 0;
    } else {
      k0 = ((const float*)maskp)[tc0] != 0.f; k1 = ((const float*)maskp)[tc1] != 0.f;
    }
    float ms0 = (k0 && tgS0 < N) ? 1.f : 0.f;
    float ms1 = (k1 && tgS1 < N) ? 1.f : 0.f;
    if (use_lds)
      wave_gather<true>(xb64, lms, lmc, msrc, mcoef, smem, rbw, B0, gcap, R0, RT,
                        loc0, cnt0, loc1, cnt1, row0, row1, ms0, ms1, xs0, xs1, ll, Nm1);
    else
      wave_gather<false>(xb64, lms, lmc, msrc, mcoef, smem, rbw, B0, gcap, R0, RT,
                         loc0, cnt0, loc1, cnt1, row0, row1, ms0, ms1, xs0, xs1, ll, Nm1);
  }
  __syncthreads();

  // MFMA: out[32 x 128] = Z(32 x 1024) @ Bstack(1024 x 128); wave owns 16 cols, 2 row-tiles
  int l15 = l & 15, lk8 = (l >> 4) * 8;
  f32x4 acc[2] = {};
  for (int ks = 0; ks < 32; ++ks) {
    int k0 = ks * 32 + lk8;
    bf16x8 a[2], bb;
#pragma unroll
    for (int rt = 0; rt < 2; ++rt) {
      int tr = rt * 16 + l15;
      int byte = tr * 2048 + ((k0 * 2) ^ ((tr & 7) << 4));
      a[rt] = *(const bf16x8*)(smem + byte);
    }
    int col = wid * 16 + l15;
    bb = *(const bf16x8*)(bmt + (size_t)col * 1024 + k0);
#pragma unroll
    for (int rt = 0; rt < 2; ++rt)
      acc[rt] = __builtin_amdgcn_mfma_f32_16x16x32_bf16(a[rt], bb, acc[rt], 0, 0, 0);
  }
#pragma unroll
  for (int rt = 0; rt < 2; ++rt) {
    int rowb = t0 + rt * 16 + (l >> 4) * 4;
    int col = wid * 16 + l15;
#pragma unroll
    for (int i = 0; i < 4; ++i) {
      int row = rowb + i;
      if (row < N) out[(size_t)row * 128 + col] = acc[rt][i];
    }
  }
}

extern "C" void kernel_launch(void* const* d_in, const int* in_sizes, int n_in,
                              void* d_out, int out_size, void* d_ws, size_t ws_size,
                              hipStream_t stream) {
  const float* x = (const float*)d_in[0];
  const void* mask = d_in[1];
  const int* source = (const int*)d_in[2];
  const int* target = (const int*)d_in[3];
  const int* etype = (const int*)d_in[4];
  const float* eweight = (const float*)d_in[5];
  const float* bases = (const float*)d_in[6];
  const float* rbw = (const float*)d_in[7];
  float* out = (float*)d_out;

  const int N = in_sizes[1];   // mask element count == num nodes
  const int E = in_sizes[2];
  const int M = 2 * E;
  const int NB = (N + 255) / 256;

  // workspace layout (256B aligned)
  char* ws = (char*)d_ws;
  size_t off = 0;
  unsigned short* xb = (unsigned short*)(ws + off); off += (size_t)N * 256;        // bf16 x
  unsigned short* bmt = (unsigned short*)(ws + off); off += 128 * 1024 * 2;        // BmatT
  unsigned* msrc = (unsigned*)(ws + off); off += (size_t)(M + 96) * 4;             // src idx
  uint4* mcoef = (uint4*)(ws + off); off += (size_t)(M + 96) * 16;                 // 8 bf16 coeffs
  int* base = (int*)(ws + off); off += ((size_t)N + 64) * 4;                       // N+1 scan
  int* cursor = (int*)(ws + off); off += ((size_t)N + 64) * 4;
  int* cnt = (int*)(ws + off); off += ((size_t)N + 64) * 4;
  int* bsum = (int*)(ws + off); off += 2048;
  int* flag = (int*)(ws + off); off += 256;

  hipMemsetAsync(cnt, 0, (size_t)N * 4, stream);
  int total8 = (N * 128) / 8;
  int CB = (total8 + 255) / 256;
  int TB = 128;  // 8 bases x 16 32x32 tiles
  int HB = (E + 255) / 256;
  prep_kernel<<<CB + TB + HB + 1, 256, 0, stream>>>(x, xb, total8, bases, bmt,
                                                    source, target, E, cnt,
                                                    (const unsigned char*)mask,
                                                    N < 8192 ? N : 8192, flag, CB, TB, HB);
  scanA_kernel<<<NB, 256, 0, stream>>>(cnt, N, bsum);
  scanB_kernel<<<NB, 256, 0, stream>>>(cnt, N, bsum, NB, base, cursor);
  scatter_kernel<<<(E + 255) / 256, 256, 0, stream>>>(source, target, etype, eweight, E,
                                                      rbw, cursor, msrc, mcoef);
  int gblk = (N + 31) / 32;
  size_t shmem = 65536 + MCP * 4 + MCP * 16 + 136;
  gather_kernel<<<gblk, 512, shmem, stream>>>((const uint2*)xb, bmt, base, msrc, mcoef,
                                              rbw, mask, flag, out, N, M + 79);
}

// Round 14
// 255.752 us; speedup vs baseline: 1.2629x; 1.2629x over previous
//
#include <hip/hip_runtime.h>

typedef __attribute__((ext_vector_type(8))) __bf16 bf16x8;
typedef __attribute__((ext_vector_type(4))) float f32x4;
typedef __attribute__((ext_vector_type(4))) unsigned uintx4;
typedef __attribute__((ext_vector_type(8))) unsigned short ushortx8;

#define MC 384   // max messages staged in LDS per block
#define MCP 448  // MC + 64 overrun pad

__device__ inline unsigned short f2bf(float f) {
  unsigned int u = __float_as_uint(f);
  unsigned int r = (u + 0x7FFFu + ((u >> 16) & 1u)) >> 16;  // RNE
  return (unsigned short)r;
}
__device__ inline float bflo(unsigned u) { return __uint_as_float(u << 16); }
__device__ inline float bfhi(unsigned u) { return __uint_as_float(u & 0xFFFF0000u); }

// ---------------- prep: fused conv | tconv(LDS transpose) | hist | detect ----------------
__global__ __launch_bounds__(256) void prep_kernel(const float* __restrict__ x,
                                                   unsigned short* __restrict__ xb, int total8,
                                                   const float* __restrict__ bases,
                                                   unsigned short* __restrict__ bmt,
                                                   const int* __restrict__ src,
                                                   const int* __restrict__ tgt, int E,
                                                   int* __restrict__ cnt,
                                                   const unsigned char* __restrict__ mask,
                                                   int mbytes, int* __restrict__ flag_out,
                                                   int CB, int TB, int HB) {
  __shared__ float tile_s[32][33];
  __shared__ int nz_off, big;
  int bid = blockIdx.x;
  if (bid < CB) {
    int id = bid * 256 + threadIdx.x;
    if (id >= total8) return;
    f32x4 f0 = __builtin_nontemporal_load(&((const f32x4*)x)[2 * id]);
    f32x4 f1 = __builtin_nontemporal_load(&((const f32x4*)x)[2 * id + 1]);
    ushortx8 r;
    r[0] = f2bf(f0[0]); r[1] = f2bf(f0[1]); r[2] = f2bf(f0[2]); r[3] = f2bf(f0[3]);
    r[4] = f2bf(f1[0]); r[5] = f2bf(f1[1]); r[6] = f2bf(f1[2]); r[7] = f2bf(f1[3]);
    ((ushortx8*)xb)[id] = r;
  } else if (bid < CB + TB) {
    // bmt[o][k]=bases[b][d][o], k=b*128+d — 32x32 LDS tile transpose, coalesced both sides
    int bid2 = bid - CB;                 // 0..127
    int b = bid2 >> 4, tile = bid2 & 15;
    int o0 = (tile >> 2) * 32, d0 = (tile & 3) * 32;
    int tx = threadIdx.x & 31, ty = threadIdx.x >> 5;
#pragma unroll
    for (int i = 0; i < 4; ++i) {
      int dl = ty + i * 8;
      tile_s[dl][tx] = bases[b * 16384 + (d0 + dl) * 128 + (o0 + tx)];
    }
    __syncthreads();
#pragma unroll
    for (int i = 0; i < 4; ++i) {
      int ol = ty + i * 8;
      bmt[(size_t)(o0 + ol) * 1024 + b * 128 + d0 + tx] = f2bf(tile_s[tx][ol]);
    }
  } else if (bid < CB + TB + HB) {
    int i = (bid - CB - TB) * 256 + threadIdx.x;
    if (i >= E) return;
    atomicAdd(&cnt[tgt[i]], 1);
    atomicAdd(&cnt[src[i]], 1);
  } else {
    if (threadIdx.x == 0) { nz_off = 0; big = 0; }
    __syncthreads();
    int lnz = 0, lbig = 0;
    for (int i = threadIdx.x; i < mbytes; i += 256) {
      unsigned char v = mask[i];
      if ((i & 3) && v) lnz++;
      if (v > 1) lbig++;
    }
    if (lnz) atomicAdd(&nz_off, lnz);
    if (lbig) atomicAdd(&big, lbig);
    __syncthreads();
    if (threadIdx.x == 0) *flag_out = (nz_off == 0) ? 0 : ((big == 0) ? 1 : 2);
  }
}

// ---------------- scanA: per-block sums ----------------
__global__ __launch_bounds__(256) void scanA_kernel(const int* __restrict__ cnt, int N,
                                                    int* __restrict__ bsum) {
  __shared__ int s[256];
  int t = threadIdx.x, i = blockIdx.x * 256 + t;
  s[t] = (i < N) ? cnt[i] : 0;
  __syncthreads();
#pragma unroll
  for (int off = 128; off > 0; off >>= 1) {
    if (t < off) s[t] += s[t + off];
    __syncthreads();
  }
  if (t == 0) bsum[blockIdx.x] = s[0];
}

// ---------------- scanB: fused block-prefix + per-element exclusive scan + cursor ----------------
__global__ __launch_bounds__(256) void scanB_kernel(const int* __restrict__ cnt, int N,
                                                    const int* __restrict__ bsum, int NB,
                                                    int* __restrict__ base,
                                                    int* __restrict__ cursor) {
  __shared__ int s[256];
  __shared__ int spref;
  int t = threadIdx.x, bid = blockIdx.x;
  int acc = 0;
  for (int i = t; i < bid; i += 256) acc += bsum[i];
  s[t] = acc;
  __syncthreads();
#pragma unroll
  for (int off = 128; off > 0; off >>= 1) {
    if (t < off) s[t] += s[t + off];
    __syncthreads();
  }
  if (t == 0) spref = s[0];
  __syncthreads();
  int pref = spref;
  __syncthreads();
  int i = bid * 256 + t;
  int c = (i < N) ? cnt[i] : 0;
  s[t] = c;
  __syncthreads();
  for (int off = 1; off < 256; off <<= 1) {
    int x = (t >= off) ? s[t - off] : 0;
    __syncthreads();
    s[t] += x;
    __syncthreads();
  }
  if (i < N) {
    int v = pref + s[t] - c;
    base[i] = v;
    cursor[i] = v;
  }
  if (bid == NB - 1 && t == 255) base[N] = pref + s[255];
}

// ---------------- scatter: messages (src) + premultiplied bf16 coeffs; pad folded in ----------------
__global__ __launch_bounds__(256) void scatter_kernel(const int* __restrict__ src,
                                                      const int* __restrict__ tgt,
                                                      const int* __restrict__ et,
                                                      const float* __restrict__ ew, int E,
                                                      const float* __restrict__ rbw,
                                                      int* __restrict__ cursor,
                                                      unsigned* __restrict__ msrc,
                                                      uint4* __restrict__ mcoef) {
  __shared__ float ctab[264];
  for (int i = threadIdx.x; i < 264; i += 256) ctab[i] = rbw[i];
  __syncthreads();
  if (blockIdx.x == 0 && threadIdx.x < 80) {  // zero pad tail (overrun region)
    msrc[2 * E + threadIdx.x] = 0u;
    mcoef[2 * E + threadIdx.x] = make_uint4(0u, 0u, 0u, 0u);
  }
  int i = blockIdx.x * 256 + threadIdx.x;
  if (i >= E) return;
  int s = src[i], g = tgt[i], r = et[i];
  float w = ew[i];
  uintx4 cv;
  {
    const float* c = &ctab[r * 8];
    cv[0] = (unsigned)f2bf(w * c[0]) | ((unsigned)f2bf(w * c[1]) << 16);
    cv[1] = (unsigned)f2bf(w * c[2]) | ((unsigned)f2bf(w * c[3]) << 16);
    cv[2] = (unsigned)f2bf(w * c[4]) | ((unsigned)f2bf(w * c[5]) << 16);
    cv[3] = (unsigned)f2bf(w * c[6]) | ((unsigned)f2bf(w * c[7]) << 16);
  }
  int s1 = atomicAdd(&cursor[g], 1);
  __builtin_nontemporal_store((unsigned)s, &msrc[s1]);
  __builtin_nontemporal_store(cv, (uintx4*)&mcoef[s1]);
  int s2 = atomicAdd(&cursor[s], 1);
  __builtin_nontemporal_store((unsigned)g, &msrc[s2]);
  __builtin_nontemporal_store(cv, (uintx4*)&mcoef[s2]);
}

// ---------------- half-wave duo message loop (2 rows per load instruction) ----------------
template <bool LDSM>
__device__ __forceinline__ void load4(const uint2* __restrict__ xb64,
                                      const unsigned* lms, const unsigned* __restrict__ gms,
                                      int B0, int gcap, int locS, int mb, int ll,
                                      unsigned Nm1, uint2 (&xq)[4]) {
#pragma unroll
  for (int s = 0; s < 4; ++s) {
    int idx = locS + mb + s;
    unsigned row;
    if (LDSM) row = lms[min(idx, MCP - 1)];
    else      row = gms[min(B0 + idx, gcap)];
    row = min(row & 0xFFFFFu, Nm1);
    xq[s] = xb64[(size_t)row * 32 + ll];
  }
}

template <bool LDSM>
__device__ __forceinline__ void fma4(const uint4* lmc, const uint4* __restrict__ gmc,
                                     int B0, int gcap, int locS, int cntS, int mb,
                                     const uint2 (&xq)[4], f32x4 (&z)[8]) {
#pragma unroll
  for (int s = 0; s < 4; ++s) {
    int idx = locS + mb + s;
    uint4 cf;
    if (LDSM) cf = lmc[min(idx, MCP - 1)];
    else      cf = gmc[min(B0 + idx, gcap)];
    unsigned vm = ((mb + s) < cntS) ? 0xFFFFFFFFu : 0u;
    unsigned c0 = cf.x & vm, c1 = cf.y & vm, c2 = cf.z & vm, c3 = cf.w & vm;
    f32x4 xv = {bflo(xq[s].x), bfhi(xq[s].x), bflo(xq[s].y), bfhi(xq[s].y)};
    float a;
    a = bflo(c0); z[0] = __builtin_elementwise_fma((f32x4){a, a, a, a}, xv, z[0]);
    a = bfhi(c0); z[1] = __builtin_elementwise_fma((f32x4){a, a, a, a}, xv, z[1]);
    a = bflo(c1); z[2] = __builtin_elementwise_fma((f32x4){a, a, a, a}, xv, z[2]);
    a = bfhi(c1); z[3] = __builtin_elementwise_fma((f32x4){a, a, a, a}, xv, z[3]);
    a = bflo(c2); z[4] = __builtin_elementwise_fma((f32x4){a, a, a, a}, xv, z[4]);
    a = bfhi(c2); z[5] = __builtin_elementwise_fma((f32x4){a, a, a, a}, xv, z[5]);
    a = bflo(c3); z[6] = __builtin_elementwise_fma((f32x4){a, a, a, a}, xv, z[6]);
    a = bfhi(c3); z[7] = __builtin_elementwise_fma((f32x4){a, a, a, a}, xv, z[7]);
  }
}

template <bool LDSM>
__device__ __forceinline__ void duo_loop(const uint2* __restrict__ xb64,
                                         const unsigned* lms, const uint4* lmc,
                                         const unsigned* __restrict__ gms,
                                         const uint4* __restrict__ gmc,
                                         int B0, int gcap, int locS, int cntS, int rmax,
                                         int ll, unsigned Nm1, f32x4 (&z)[8]) {
  int rounds = (rmax + 3) >> 2;
  if (rounds <= 0) return;
  uint2 xq0[4], xq1[4];
  load4<LDSM>(xb64, lms, gms, B0, gcap, locS, 0, ll, Nm1, xq0);
  for (int r = 0; r < rounds; ++r) {
    if ((r & 1) == 0) {
      if (r + 1 < rounds) load4<LDSM>(xb64, lms, gms, B0, gcap, locS, (r + 1) * 4, ll, Nm1, xq1);
      fma4<LDSM>(lmc, gmc, B0, gcap, locS, cntS, r * 4, xq0, z);
    } else {
      if (r + 1 < rounds) load4<LDSM>(xb64, lms, gms, B0, gcap, locS, (r + 1) * 4, ll, Nm1, xq0);
      fma4<LDSM>(lmc, gmc, B0, gcap, locS, cntS, r * 4, xq1, z);
    }
  }
}

// ---------------- K: block-staged meta + half-wave dwordx2 gather + block MFMA ----------------
// block = 512 thr (8 waves), owns 32 targets; wave owns 4 targets as 2 duos (A,B per half-wave).
// LDS: z 32x2048B (65536) | lms u32[MCP] | lmc uint4[MCP] | lbase int[33]
__global__ __launch_bounds__(512, 4) void gather_kernel(
    const uint2* __restrict__ xb64, const unsigned short* __restrict__ bmt,
    const int* __restrict__ base, const unsigned* __restrict__ msrc,
    const uint4* __restrict__ mcoef, const float* __restrict__ rbw,
    const void* __restrict__ maskp, const int* __restrict__ flag_p,
    float* __restrict__ out, int N, int gcap) {
  extern __shared__ char smem[];
  unsigned* lms = (unsigned*)(smem + 65536);
  uint4* lmc = (uint4*)(smem + 65536 + MCP * 4);
  int* lbase = (int*)(smem + 65536 + MCP * 4 + MCP * 16);
  int t = threadIdx.x;
  int wid = t >> 6, l = t & 63;
  int hw = l >> 5, ll = l & 31;
  int t0 = blockIdx.x * 32;
  int flag = *flag_p;  // uniform
  unsigned Nm1 = (unsigned)(N - 1);

  if (t < 33) lbase[t] = base[min(t0 + t, N)];
  int B0 = __builtin_amdgcn_readfirstlane(base[min(t0, N)]);
  int B1 = __builtin_amdgcn_readfirstlane(base[min(t0 + 32, N)]);
  int nm = B1 - B0;
  bool use_lds = (nm <= MC);
  if (use_lds) {
    for (int i = t; i < nm; i += 512) {
      lms[i] = __builtin_nontemporal_load(&msrc[B0 + i]);
      uintx4 v = __builtin_nontemporal_load((const uintx4*)&mcoef[B0 + i]);
      lmc[i] = make_uint4(v[0], v[1], v[2], v[3]);
    }
    int pz = nm + t;
    if (t < 64 && pz < MCP) {
      lms[pz] = 0u;
      lmc[pz] = make_uint4(0u, 0u, 0u, 0u);
    }
  }
  __syncthreads();

  for (int p = 0; p < 2; ++p) {
    int jA = wid * 4 + p * 2, jB = jA + 1;
    int tgA = t0 + jA, tgB = t0 + jB;
    int begA = __builtin_amdgcn_readfirstlane(lbase[jA]);
    int begB = __builtin_amdgcn_readfirstlane(lbase[jB]);
    int endB = __builtin_amdgcn_readfirstlane(lbase[jB + 1]);
    int cntA = (tgA < N) ? (begB - begA) : 0;
    int cntB = (tgB < N) ? (endB - begB) : 0;
    int locA = begA - B0, locB = begB - B0;
    // per-half selections
    int tgS = hw ? tgB : tgA;
    int tcS = min(tgS, N - 1);
    int locS = hw ? locB : locA;
    int cntS = hw ? cntB : cntA;
    // self-loop seed
    uint2 xs = xb64[(size_t)tcS * 32 + ll];
    int keep;
    if (flag == 0)      keep = ((const int*)maskp)[tcS] != 0;
    else if (flag == 1) keep = ((const unsigned char*)maskp)[tcS] != 0;
    else                keep = ((const float*)maskp)[tcS] != 0.f;
    float ms = (keep && tgS < N) ? 1.f : 0.f;
    f32x4 xv0 = {bflo(xs.x), bfhi(xs.x), bflo(xs.y), bfhi(xs.y)};
    f32x4 z[8];
#pragma unroll
    for (int b = 0; b < 8; ++b) {
      float a = ms * rbw[256 + b];  // uniform scalar load
      z[b] = (f32x4){a, a, a, a} * xv0;
    }
    int rmax = max(cntA, cntB);
    if (use_lds)
      duo_loop<true>(xb64, lms, lmc, msrc, mcoef, B0, gcap, locS, cntS, rmax, ll, Nm1, z);
    else
      duo_loop<false>(xb64, lms, lmc, msrc, mcoef, B0, gcap, locS, cntS, rmax, ll, Nm1, z);
    // flush z row to LDS (bf16, XOR swizzle); lane covers dims 4*ll..4*ll+3 of its target
    int rowS = hw ? jB : jA;
#pragma unroll
    for (int b = 0; b < 8; ++b) {
      unsigned d0 = (unsigned)f2bf(z[b][0]) | ((unsigned)f2bf(z[b][1]) << 16);
      unsigned d1 = (unsigned)f2bf(z[b][2]) | ((unsigned)f2bf(z[b][3]) << 16);
      int byte = rowS * 2048 + ((b * 256 + ll * 8) ^ ((rowS & 7) << 4));
      *(uint2*)(smem + byte) = make_uint2(d0, d1);
    }
  }
  __syncthreads();

  // MFMA: out[32 x 128] = Z(32 x 1024) @ Bstack(1024 x 128); wave owns 16 cols, 2 row-tiles
  int l15 = l & 15, lk8 = (l >> 4) * 8;
  f32x4 acc[2] = {};
  for (int ks = 0; ks < 32; ++ks) {
    int k0 = ks * 32 + lk8;
    bf16x8 a[2], bb;
#pragma unroll
    for (int rt = 0; rt < 2; ++rt) {
      int tr = rt * 16 + l15;
      int byte = tr * 2048 + ((k0 * 2) ^ ((tr & 7) << 4));
      a[rt] = *(const bf16x8*)(smem + byte);
    }
    int col = wid * 16 + l15;
    bb = *(const bf16x8*)(bmt + (size_t)col * 1024 + k0);
#pragma unroll
    for (int rt = 0; rt < 2; ++rt)
      acc[rt] = __builtin_amdgcn_mfma_f32_16x16x32_bf16(a[rt], bb, acc[rt], 0, 0, 0);
  }
#pragma unroll
  for (int rt = 0; rt < 2; ++rt) {
    int rowb = t0 + rt * 16 + (l >> 4) * 4;
    int col = wid * 16 + l15;
#pragma unroll
    for (int i = 0; i < 4; ++i) {
      int row = rowb + i;
      if (row < N) __builtin_nontemporal_store(acc[rt][i], &out[(size_t)row * 128 + col]);
    }
  }
}

extern "C" void kernel_launch(void* const* d_in, const int* in_sizes, int n_in,
                              void* d_out, int out_size, void* d_ws, size_t ws_size,
                              hipStream_t stream) {
  const float* x = (const float*)d_in[0];
  const void* mask = d_in[1];
  const int* source = (const int*)d_in[2];
  const int* target = (const int*)d_in[3];
  const int* etype = (const int*)d_in[4];
  const float* eweight = (const float*)d_in[5];
  const float* bases = (const float*)d_in[6];
  const float* rbw = (const float*)d_in[7];
  float* out = (float*)d_out;

  const int N = in_sizes[1];   // mask element count == num nodes
  const int E = in_sizes[2];
  const int M = 2 * E;
  const int NB = (N + 255) / 256;

  // workspace layout (256B aligned)
  char* ws = (char*)d_ws;
  size_t off = 0;
  unsigned short* xb = (unsigned short*)(ws + off); off += (size_t)N * 256;        // bf16 x
  unsigned short* bmt = (unsigned short*)(ws + off); off += 128 * 1024 * 2;        // BmatT
  unsigned* msrc = (unsigned*)(ws + off); off += (size_t)(M + 96) * 4;             // src idx
  uint4* mcoef = (uint4*)(ws + off); off += (size_t)(M + 96) * 16;                 // 8 bf16 coeffs
  int* base = (int*)(ws + off); off += ((size_t)N + 64) * 4;                       // N+1 scan
  int* cursor = (int*)(ws + off); off += ((size_t)N + 64) * 4;
  int* cnt = (int*)(ws + off); off += ((size_t)N + 64) * 4;
  int* bsum = (int*)(ws + off); off += 2048;
  int* flag = (int*)(ws + off); off += 256;

  hipMemsetAsync(cnt, 0, (size_t)N * 4, stream);
  int total8 = (N * 128) / 8;
  int CB = (total8 + 255) / 256;
  int TB = 128;  // 8 bases x 16 32x32 tiles
  int HB = (E + 255) / 256;
  prep_kernel<<<CB + TB + HB + 1, 256, 0, stream>>>(x, xb, total8, bases, bmt,
                                                    source, target, E, cnt,
                                                    (const unsigned char*)mask,
                                                    N < 8192 ? N : 8192, flag, CB, TB, HB);
  scanA_kernel<<<NB, 256, 0, stream>>>(cnt, N, bsum);
  scanB_kernel<<<NB, 256, 0, stream>>>(cnt, N, bsum, NB, base, cursor);
  scatter_kernel<<<(E + 255) / 256, 256, 0, stream>>>(source, target, etype, eweight, E,
                                                      rbw, cursor, msrc, mcoef);
  int gblk = (N + 31) / 32;
  size_t shmem = 65536 + MCP * 4 + MCP * 16 + 136;
  gather_kernel<<<gblk, 512, shmem, stream>>>((const uint2*)xb, bmt, base, msrc, mcoef,
                                              rbw, mask, flag, out, N, M + 79);
}

// Round 15
// 238.084 us; speedup vs baseline: 1.3566x; 1.0742x over previous
//
#include <hip/hip_runtime.h>

typedef __attribute__((ext_vector_type(8))) __bf16 bf16x8;
typedef __attribute__((ext_vector_type(4))) float f32x4;
typedef __attribute__((ext_vector_type(8))) unsigned short ushortx8;

#define MC 384   // max messages staged in LDS per block
#define MCP 448  // MC + 64 overrun pad

__device__ inline unsigned short f2bf(float f) {
  unsigned int u = __float_as_uint(f);
  unsigned int r = (u + 0x7FFFu + ((u >> 16) & 1u)) >> 16;  // RNE
  return (unsigned short)r;
}
__device__ inline float bflo(unsigned u) { return __uint_as_float(u << 16); }
__device__ inline float bfhi(unsigned u) { return __uint_as_float(u & 0xFFFF0000u); }

// ---------------- prep: fused conv | tconv(LDS transpose) | hist | detect ----------------
__global__ __launch_bounds__(256) void prep_kernel(const float* __restrict__ x,
                                                   unsigned short* __restrict__ xb, int total8,
                                                   const float* __restrict__ bases,
                                                   unsigned short* __restrict__ bmt,
                                                   const int* __restrict__ src,
                                                   const int* __restrict__ tgt, int E,
                                                   int* __restrict__ cnt,
                                                   const unsigned char* __restrict__ mask,
                                                   int mbytes, int* __restrict__ flag_out,
                                                   int CB, int TB, int HB) {
  __shared__ float tile_s[32][33];
  __shared__ int nz_off, big;
  int bid = blockIdx.x;
  if (bid < CB) {
    int id = bid * 256 + threadIdx.x;
    if (id >= total8) return;
    f32x4 f0 = ((const f32x4*)x)[2 * id];
    f32x4 f1 = ((const f32x4*)x)[2 * id + 1];
    ushortx8 r;
    r[0] = f2bf(f0[0]); r[1] = f2bf(f0[1]); r[2] = f2bf(f0[2]); r[3] = f2bf(f0[3]);
    r[4] = f2bf(f1[0]); r[5] = f2bf(f1[1]); r[6] = f2bf(f1[2]); r[7] = f2bf(f1[3]);
    ((ushortx8*)xb)[id] = r;
  } else if (bid < CB + TB) {
    // bmt[o][k]=bases[b][d][o], k=b*128+d — 32x32 LDS tile transpose, coalesced both sides
    int bid2 = bid - CB;                 // 0..127
    int b = bid2 >> 4, tile = bid2 & 15;
    int o0 = (tile >> 2) * 32, d0 = (tile & 3) * 32;
    int tx = threadIdx.x & 31, ty = threadIdx.x >> 5;
#pragma unroll
    for (int i = 0; i < 4; ++i) {
      int dl = ty + i * 8;
      tile_s[dl][tx] = bases[b * 16384 + (d0 + dl) * 128 + (o0 + tx)];
    }
    __syncthreads();
#pragma unroll
    for (int i = 0; i < 4; ++i) {
      int ol = ty + i * 8;
      bmt[(size_t)(o0 + ol) * 1024 + b * 128 + d0 + tx] = f2bf(tile_s[tx][ol]);
    }
  } else if (bid < CB + TB + HB) {
    int i = (bid - CB - TB) * 256 + threadIdx.x;
    if (i >= E) return;
    atomicAdd(&cnt[tgt[i]], 1);
    atomicAdd(&cnt[src[i]], 1);
  } else {
    if (threadIdx.x == 0) { nz_off = 0; big = 0; }
    __syncthreads();
    int lnz = 0, lbig = 0;
    for (int i = threadIdx.x; i < mbytes; i += 256) {
      unsigned char v = mask[i];
      if ((i & 3) && v) lnz++;
      if (v > 1) lbig++;
    }
    if (lnz) atomicAdd(&nz_off, lnz);
    if (lbig) atomicAdd(&big, lbig);
    __syncthreads();
    if (threadIdx.x == 0) *flag_out = (nz_off == 0) ? 0 : ((big == 0) ? 1 : 2);
  }
}

// ---------------- scanA: per-block sums ----------------
__global__ __launch_bounds__(256) void scanA_kernel(const int* __restrict__ cnt, int N,
                                                    int* __restrict__ bsum) {
  __shared__ int s[256];
  int t = threadIdx.x, i = blockIdx.x * 256 + t;
  s[t] = (i < N) ? cnt[i] : 0;
  __syncthreads();
#pragma unroll
  for (int off = 128; off > 0; off >>= 1) {
    if (t < off) s[t] += s[t + off];
    __syncthreads();
  }
  if (t == 0) bsum[blockIdx.x] = s[0];
}

// ---------------- scanB: fused block-prefix + per-element exclusive scan + cursor ----------------
__global__ __launch_bounds__(256) void scanB_kernel(const int* __restrict__ cnt, int N,
                                                    const int* __restrict__ bsum, int NB,
                                                    int* __restrict__ base,
                                                    int* __restrict__ cursor) {
  __shared__ int s[256];
  __shared__ int spref;
  int t = threadIdx.x, bid = blockIdx.x;
  int acc = 0;
  for (int i = t; i < bid; i += 256) acc += bsum[i];
  s[t] = acc;
  __syncthreads();
#pragma unroll
  for (int off = 128; off > 0; off >>= 1) {
    if (t < off) s[t] += s[t + off];
    __syncthreads();
  }
  if (t == 0) spref = s[0];
  __syncthreads();
  int pref = spref;
  __syncthreads();
  int i = bid * 256 + t;
  int c = (i < N) ? cnt[i] : 0;
  s[t] = c;
  __syncthreads();
  for (int off = 1; off < 256; off <<= 1) {
    int x = (t >= off) ? s[t - off] : 0;
    __syncthreads();
    s[t] += x;
    __syncthreads();
  }
  if (i < N) {
    int v = pref + s[t] - c;
    base[i] = v;
    cursor[i] = v;
  }
  if (bid == NB - 1 && t == 255) base[N] = pref + s[255];
}

// ---------------- scatter: messages (src) + premultiplied bf16 coeffs; pad folded in ----------------
__global__ __launch_bounds__(256) void scatter_kernel(const int* __restrict__ src,
                                                      const int* __restrict__ tgt,
                                                      const int* __restrict__ et,
                                                      const float* __restrict__ ew, int E,
                                                      const float* __restrict__ rbw,
                                                      int* __restrict__ cursor,
                                                      unsigned* __restrict__ msrc,
                                                      uint4* __restrict__ mcoef) {
  __shared__ float ctab[264];
  for (int i = threadIdx.x; i < 264; i += 256) ctab[i] = rbw[i];
  __syncthreads();
  if (blockIdx.x == 0 && threadIdx.x < 80) {  // zero pad tail (overrun region)
    msrc[2 * E + threadIdx.x] = 0u;
    mcoef[2 * E + threadIdx.x] = make_uint4(0u, 0u, 0u, 0u);
  }
  int i = blockIdx.x * 256 + threadIdx.x;
  if (i >= E) return;
  int s = src[i], g = tgt[i], r = et[i];
  float w = ew[i];
  uint4 cv;
  {
    const float* c = &ctab[r * 8];
    cv.x = (unsigned)f2bf(w * c[0]) | ((unsigned)f2bf(w * c[1]) << 16);
    cv.y = (unsigned)f2bf(w * c[2]) | ((unsigned)f2bf(w * c[3]) << 16);
    cv.z = (unsigned)f2bf(w * c[4]) | ((unsigned)f2bf(w * c[5]) << 16);
    cv.w = (unsigned)f2bf(w * c[6]) | ((unsigned)f2bf(w * c[7]) << 16);
  }
  int s1 = atomicAdd(&cursor[g], 1);
  msrc[s1] = (unsigned)s;
  mcoef[s1] = cv;
  int s2 = atomicAdd(&cursor[s], 1);
  msrc[s2] = (unsigned)g;
  mcoef[s2] = cv;
}

// ---------------- half-wave duo message loop (2 rows per load instruction) ----------------
template <bool LDSM>
__device__ __forceinline__ void load4(const uint2* __restrict__ xb64,
                                      const unsigned* lms, const unsigned* __restrict__ gms,
                                      int B0, int gcap, int locS, int mb, int ll,
                                      unsigned Nm1, uint2 (&xq)[4]) {
#pragma unroll
  for (int s = 0; s < 4; ++s) {
    int idx = locS + mb + s;
    unsigned row;
    if (LDSM) row = lms[min(idx, MCP - 1)];
    else      row = gms[min(B0 + idx, gcap)];
    row = min(row & 0xFFFFFu, Nm1);
    xq[s] = xb64[(size_t)row * 32 + ll];
  }
}

template <bool LDSM>
__device__ __forceinline__ void fma4(const uint4* lmc, const uint4* __restrict__ gmc,
                                     int B0, int gcap, int locS, int cntS, int mb,
                                     const uint2 (&xq)[4], f32x4 (&z)[8]) {
#pragma unroll
  for (int s = 0; s < 4; ++s) {
    int idx = locS + mb + s;
    uint4 cf;
    if (LDSM) cf = lmc[min(idx, MCP - 1)];
    else      cf = gmc[min(B0 + idx, gcap)];
    unsigned vm = ((mb + s) < cntS) ? 0xFFFFFFFFu : 0u;
    unsigned c0 = cf.x & vm, c1 = cf.y & vm, c2 = cf.z & vm, c3 = cf.w & vm;
    f32x4 xv = {bflo(xq[s].x), bfhi(xq[s].x), bflo(xq[s].y), bfhi(xq[s].y)};
    float a;
    a = bflo(c0); z[0] = __builtin_elementwise_fma((f32x4){a, a, a, a}, xv, z[0]);
    a = bfhi(c0); z[1] = __builtin_elementwise_fma((f32x4){a, a, a, a}, xv, z[1]);
    a = bflo(c1); z[2] = __builtin_elementwise_fma((f32x4){a, a, a, a}, xv, z[2]);
    a = bfhi(c1); z[3] = __builtin_elementwise_fma((f32x4){a, a, a, a}, xv, z[3]);
    a = bflo(c2); z[4] = __builtin_elementwise_fma((f32x4){a, a, a, a}, xv, z[4]);
    a = bfhi(c2); z[5] = __builtin_elementwise_fma((f32x4){a, a, a, a}, xv, z[5]);
    a = bflo(c3); z[6] = __builtin_elementwise_fma((f32x4){a, a, a, a}, xv, z[6]);
    a = bfhi(c3); z[7] = __builtin_elementwise_fma((f32x4){a, a, a, a}, xv, z[7]);
  }
}

template <bool LDSM>
__device__ __forceinline__ void duo_loop(const uint2* __restrict__ xb64,
                                         const unsigned* lms, const uint4* lmc,
                                         const unsigned* __restrict__ gms,
                                         const uint4* __restrict__ gmc,
                                         int B0, int gcap, int locS, int cntS, int rmax,
                                         int ll, unsigned Nm1, f32x4 (&z)[8]) {
  int rounds = (rmax + 3) >> 2;
  if (rounds <= 0) return;
  uint2 xq0[4], xq1[4];
  load4<LDSM>(xb64, lms, gms, B0, gcap, locS, 0, ll, Nm1, xq0);
  for (int r = 0; r < rounds; ++r) {
    if ((r & 1) == 0) {
      if (r + 1 < rounds) load4<LDSM>(xb64, lms, gms, B0, gcap, locS, (r + 1) * 4, ll, Nm1, xq1);
      fma4<LDSM>(lmc, gmc, B0, gcap, locS, cntS, r * 4, xq0, z);
    } else {
      if (r + 1 < rounds) load4<LDSM>(xb64, lms, gms, B0, gcap, locS, (r + 1) * 4, ll, Nm1, xq0);
      fma4<LDSM>(lmc, gmc, B0, gcap, locS, cntS, r * 4, xq1, z);
    }
  }
}

// ---------------- K: block-staged meta + half-wave dwordx2 gather + block MFMA ----------------
// block = 512 thr (8 waves), owns 32 targets; wave owns 4 targets as 2 duos (A,B per half-wave).
// LDS: z 32x2048B (65536) | lms u32[MCP] | lmc uint4[MCP] | lbase int[33]
__global__ __launch_bounds__(512, 4) void gather_kernel(
    const uint2* __restrict__ xb64, const unsigned short* __restrict__ bmt,
    const int* __restrict__ base, const unsigned* __restrict__ msrc,
    const uint4* __restrict__ mcoef, const float* __restrict__ rbw,
    const void* __restrict__ maskp, const int* __restrict__ flag_p,
    float* __restrict__ out, int N, int gcap) {
  extern __shared__ char smem[];
  unsigned* lms = (unsigned*)(smem + 65536);
  uint4* lmc = (uint4*)(smem + 65536 + MCP * 4);
  int* lbase = (int*)(smem + 65536 + MCP * 4 + MCP * 16);
  int t = threadIdx.x;
  int wid = t >> 6, l = t & 63;
  int hw = l >> 5, ll = l & 31;
  int t0 = blockIdx.x * 32;
  int flag = *flag_p;  // uniform
  unsigned Nm1 = (unsigned)(N - 1);

  if (t < 33) lbase[t] = base[min(t0 + t, N)];
  int B0 = __builtin_amdgcn_readfirstlane(base[min(t0, N)]);
  int B1 = __builtin_amdgcn_readfirstlane(base[min(t0 + 32, N)]);
  int nm = B1 - B0;
  bool use_lds = (nm <= MC);
  if (use_lds) {
    for (int i = t; i < nm; i += 512) {
      lms[i] = msrc[B0 + i];
      lmc[i] = mcoef[B0 + i];
    }
    int pz = nm + t;
    if (t < 64 && pz < MCP) {
      lms[pz] = 0u;
      lmc[pz] = make_uint4(0u, 0u, 0u, 0u);
    }
  }
  __syncthreads();

  for (int p = 0; p < 2; ++p) {
    int jA = wid * 4 + p * 2, jB = jA + 1;
    int tgA = t0 + jA, tgB = t0 + jB;
    int begA = __builtin_amdgcn_readfirstlane(lbase[jA]);
    int begB = __builtin_amdgcn_readfirstlane(lbase[jB]);
    int endB = __builtin_amdgcn_readfirstlane(lbase[jB + 1]);
    int cntA = (tgA < N) ? (begB - begA) : 0;
    int cntB = (tgB < N) ? (endB - begB) : 0;
    int locA = begA - B0, locB = begB - B0;
    // per-half selections
    int tgS = hw ? tgB : tgA;
    int tcS = min(tgS, N - 1);
    int locS = hw ? locB : locA;
    int cntS = hw ? cntB : cntA;
    // self-loop seed
    uint2 xs = xb64[(size_t)tcS * 32 + ll];
    int keep;
    if (flag == 0)      keep = ((const int*)maskp)[tcS] != 0;
    else if (flag == 1) keep = ((const unsigned char*)maskp)[tcS] != 0;
    else                keep = ((const float*)maskp)[tcS] != 0.f;
    float ms = (keep && tgS < N) ? 1.f : 0.f;
    f32x4 xv0 = {bflo(xs.x), bfhi(xs.x), bflo(xs.y), bfhi(xs.y)};
    f32x4 z[8];
#pragma unroll
    for (int b = 0; b < 8; ++b) {
      float a = ms * rbw[256 + b];  // uniform scalar load
      z[b] = (f32x4){a, a, a, a} * xv0;
    }
    int rmax = max(cntA, cntB);
    if (use_lds)
      duo_loop<true>(xb64, lms, lmc, msrc, mcoef, B0, gcap, locS, cntS, rmax, ll, Nm1, z);
    else
      duo_loop<false>(xb64, lms, lmc, msrc, mcoef, B0, gcap, locS, cntS, rmax, ll, Nm1, z);
    // flush z row to LDS (bf16, XOR swizzle); lane covers dims 4*ll..4*ll+3 of its target
    int rowS = hw ? jB : jA;
#pragma unroll
    for (int b = 0; b < 8; ++b) {
      unsigned d0 = (unsigned)f2bf(z[b][0]) | ((unsigned)f2bf(z[b][1]) << 16);
      unsigned d1 = (unsigned)f2bf(z[b][2]) | ((unsigned)f2bf(z[b][3]) << 16);
      int byte = rowS * 2048 + ((b * 256 + ll * 8) ^ ((rowS & 7) << 4));
      *(uint2*)(smem + byte) = make_uint2(d0, d1);
    }
  }
  __syncthreads();

  // MFMA: out[32 x 128] = Z(32 x 1024) @ Bstack(1024 x 128); wave owns 16 cols, 2 row-tiles
  int l15 = l & 15, lk8 = (l >> 4) * 8;
  f32x4 acc[2] = {};
  for (int ks = 0; ks < 32; ++ks) {
    int k0 = ks * 32 + lk8;
    bf16x8 a[2], bb;
#pragma unroll
    for (int rt = 0; rt < 2; ++rt) {
      int tr = rt * 16 + l15;
      int byte = tr * 2048 + ((k0 * 2) ^ ((tr & 7) << 4));
      a[rt] = *(const bf16x8*)(smem + byte);
    }
    int col = wid * 16 + l15;
    bb = *(const bf16x8*)(bmt + (size_t)col * 1024 + k0);
#pragma unroll
    for (int rt = 0; rt < 2; ++rt)
      acc[rt] = __builtin_amdgcn_mfma_f32_16x16x32_bf16(a[rt], bb, acc[rt], 0, 0, 0);
  }
#pragma unroll
  for (int rt = 0; rt < 2; ++rt) {
    int rowb = t0 + rt * 16 + (l >> 4) * 4;
    int col = wid * 16 + l15;
#pragma unroll
    for (int i = 0; i < 4; ++i) {
      int row = rowb + i;
      if (row < N) out[(size_t)row * 128 + col] = acc[rt][i];
    }
  }
}

extern "C" void kernel_launch(void* const* d_in, const int* in_sizes, int n_in,
                              void* d_out, int out_size, void* d_ws, size_t ws_size,
                              hipStream_t stream) {
  const float* x = (const float*)d_in[0];
  const void* mask = d_in[1];
  const int* source = (const int*)d_in[2];
  const int* target = (const int*)d_in[3];
  const int* etype = (const int*)d_in[4];
  const float* eweight = (const float*)d_in[5];
  const float* bases = (const float*)d_in[6];
  const float* rbw = (const float*)d_in[7];
  float* out = (float*)d_out;

  const int N = in_sizes[1];   // mask element count == num nodes
  const int E = in_sizes[2];
  const int M = 2 * E;
  const int NB = (N + 255) / 256;

  // workspace layout (256B aligned)
  char* ws = (char*)d_ws;
  size_t off = 0;
  unsigned short* xb = (unsigned short*)(ws + off); off += (size_t)N * 256;        // bf16 x
  unsigned short* bmt = (unsigned short*)(ws + off); off += 128 * 1024 * 2;        // BmatT
  unsigned* msrc = (unsigned*)(ws + off); off += (size_t)(M + 96) * 4;             // src idx
  uint4* mcoef = (uint4*)(ws + off); off += (size_t)(M + 96) * 16;                 // 8 bf16 coeffs
  int* base = (int*)(ws + off); off += ((size_t)N + 64) * 4;                       // N+1 scan
  int* cursor = (int*)(ws + off); off += ((size_t)N + 64) * 4;
  int* cnt = (int*)(ws + off); off += ((size_t)N + 64) * 4;
  int* bsum = (int*)(ws + off); off += 2048;
  int* flag = (int*)(ws + off); off += 256;

  hipMemsetAsync(cnt, 0, (size_t)N * 4, stream);
  int total8 = (N * 128) / 8;
  int CB = (total8 + 255) / 256;
  int TB = 128;  // 8 bases x 16 32x32 tiles
  int HB = (E + 255) / 256;
  prep_kernel<<<CB + TB + HB + 1, 256, 0, stream>>>(x, xb, total8, bases, bmt,
                                                    source, target, E, cnt,
                                                    (const unsigned char*)mask,
                                                    N < 8192 ? N : 8192, flag, CB, TB, HB);
  scanA_kernel<<<NB, 256, 0, stream>>>(cnt, N, bsum);
  scanB_kernel<<<NB, 256, 0, stream>>>(cnt, N, bsum, NB, base, cursor);
  scatter_kernel<<<(E + 255) / 256, 256, 0, stream>>>(source, target, etype, eweight, E,
                                                      rbw, cursor, msrc, mcoef);
  int gblk = (N + 31) / 32;
  size_t shmem = 65536 + MCP * 4 + MCP * 16 + 136;
  gather_kernel<<<gblk, 512, shmem, stream>>>((const uint2*)xb, bmt, base, msrc, mcoef,
                                              rbw, mask, flag, out, N, M + 79);
}